// Round 7
// baseline (59.313 us; speedup 1.0000x reference)
//
#include <hip/hip_runtime.h>
#include <stdint.h>

#define T_DIM 8192
#define J_DIM 1024
#define D_DIM 256

typedef __bf16 bf16x8 __attribute__((ext_vector_type(8)));
typedef float f32x4 __attribute__((ext_vector_type(4)));
typedef unsigned short u16x8 __attribute__((ext_vector_type(8)));
typedef unsigned short u16x4 __attribute__((ext_vector_type(4)));

__device__ inline unsigned short f2bf(float x) {
    unsigned u = __builtin_bit_cast(unsigned, x);
    u += 0x7FFFu + ((u >> 16) & 1u);
    return (unsigned short)(u >> 16);
}

// async global->LDS, 16B/lane; LDS dest = wave-uniform base + lane*16 (linear).
__device__ inline void gll16(const void* g, void* l) {
    __builtin_amdgcn_global_load_lds(
        (const __attribute__((address_space(1))) unsigned int*)g,
        (__attribute__((address_space(3))) unsigned int*)l, 16, 0, 0);
}

__device__ inline void wait_lgkm0_bar() {
    asm volatile("s_waitcnt lgkmcnt(0)" ::: "memory");
    __builtin_amdgcn_sched_barrier(0);
    __builtin_amdgcn_s_barrier();
    __builtin_amdgcn_sched_barrier(0);
}
__device__ inline void wait_all_bar() {
    asm volatile("s_waitcnt vmcnt(0) lgkmcnt(0)" ::: "memory");
    __builtin_amdgcn_sched_barrier(0);
    __builtin_amdgcn_s_barrier();
    __builtin_amdgcn_sched_barrier(0);
}

// K0: query prep: Qb row-major bf16, QT transposed bf16, qw. Block 256 zeroes ht.
__global__ __launch_bounds__(256) void prep_q(const float* __restrict__ qry,
                                              const float* __restrict__ w,
                                              unsigned short* __restrict__ Qb,
                                              unsigned short* __restrict__ QT,
                                              float* __restrict__ qw,
                                              float* __restrict__ ht) {
    if (blockIdx.x == 256) {
        ht[threadIdx.x] = 0.0f;
        return;
    }
    int wid = threadIdx.x >> 6, lane = threadIdx.x & 63;
    int j = blockIdx.x * 4 + wid;
    float4 c  = *(const float4*)(qry + (size_t)j * D_DIM + lane * 4);
    float4 wq = *(const float4*)(w + D_DIM + lane * 4);
    u16x4 qv;
    qv[0] = f2bf(c.x);
    qv[1] = f2bf(c.y);
    qv[2] = f2bf(c.z);
    qv[3] = f2bf(c.w);
    *(u16x4*)(Qb + (size_t)j * D_DIM + lane * 4) = qv;
    int d0 = lane * 4;
    QT[(size_t)(d0 + 0) * J_DIM + j] = qv[0];
    QT[(size_t)(d0 + 1) * J_DIM + j] = qv[1];
    QT[(size_t)(d0 + 2) * J_DIM + j] = qv[2];
    QT[(size_t)(d0 + 3) * J_DIM + j] = qv[3];
    float s = c.x * wq.x + c.y * wq.y + c.z * wq.z + c.w * wq.w;
    #pragma unroll
    for (int o = 1; o < 64; o <<= 1) s += __shfl_xor(s, o);
    if (lane == 0) qw[j] = s;
}

// K1: fused flash main. 256 blocks x 512 thr (8 waves: 2 wm x 4 nw), 32 t-rows/block,
// full J per block -> exact stats, no P/Cm in global. A (ctx*w_m) lives in registers.
// Double-buffered Qb/Qt j-tiles (64 j) staged via global_load_lds; 2 raw barriers/iter,
// vmcnt drained only at iter end (staging overlaps S-phase).
__global__ __launch_bounds__(512) void fused_main(
        const float* __restrict__ ctx, const float* __restrict__ w,
        const unsigned short* __restrict__ Qb, const unsigned short* __restrict__ QT,
        const float* __restrict__ qw, float* __restrict__ ht,
        float* __restrict__ G) {
    extern __shared__ char smem[];
    unsigned short* qb0 = (unsigned short*)smem;             // 2 x [64][256] bf16, 32 KB each
    unsigned short* qt0 = (unsigned short*)(smem + 65536);   // 2 x [256][64] bf16, 32 KB each
    unsigned short* PS  = (unsigned short*)(smem + 131072);  // [32][64] bf16, 4 KB
    float* statS = (float*)(smem + 135168);                  // [4][32]
    float* statM = (float*)(smem + 135680);                  // [4][32]
    float* cwS   = (float*)(smem + 136192);                  // [32]
    float* linvS = (float*)(smem + 136320);                  // [32]
    float* bS    = (float*)(smem + 136448);                  // [32]
    float* ctxS  = (float*)smem;                             // epilogue alias of qb0 area

    const int tid = threadIdx.x, lane = tid & 63, wv = tid >> 6;
    const int cidx = lane & 15, rgrp = lane >> 4;
    const int wm = wv >> 2, nw = wv & 3;
    const int t0 = blockIdx.x * 32;

    // ---- prologue: A-frags (Cm rows in regs) + cw row-dots
    bf16x8 af[8];
    {
        int arow = t0 + wm * 16 + cidx;
        const float* crow = ctx + (size_t)arow * D_DIM;
        float pc = 0.f;
        #pragma unroll
        for (int f = 0; f < 8; ++f) {
            int k = f * 32 + rgrp * 8;
            float4 a0 = *(const float4*)(crow + k);
            float4 a1 = *(const float4*)(crow + k + 4);
            float4 m0 = *(const float4*)(w + 2 * D_DIM + k);
            float4 m1 = *(const float4*)(w + 2 * D_DIM + k + 4);
            float4 c0 = *(const float4*)(w + k);
            float4 c1 = *(const float4*)(w + k + 4);
            u16x8 t8;
            t8[0] = f2bf(a0.x * m0.x); t8[1] = f2bf(a0.y * m0.y);
            t8[2] = f2bf(a0.z * m0.z); t8[3] = f2bf(a0.w * m0.w);
            t8[4] = f2bf(a1.x * m1.x); t8[5] = f2bf(a1.y * m1.y);
            t8[6] = f2bf(a1.z * m1.z); t8[7] = f2bf(a1.w * m1.w);
            af[f] = __builtin_bit_cast(bf16x8, t8);
            pc += a0.x * c0.x + a0.y * c0.y + a0.z * c0.z + a0.w * c0.w
                + a1.x * c1.x + a1.y * c1.y + a1.z * c1.z + a1.w * c1.w;
        }
        pc += __shfl_xor(pc, 16);
        pc += __shfl_xor(pc, 32);
        if (nw == 0 && rgrp == 0) cwS[wm * 16 + cidx] = pc;
    }

    // staging: linear LDS dest, inverse-swizzled global source (both-sides rule)
    auto stage_tiles = [&](int bufsel, int j0) {
        unsigned short* qb = qb0 + bufsel * 16384;
        unsigned short* qt = qt0 + bufsel * 16384;
        #pragma unroll
        for (int i = 0; i < 4; ++i) {             // QbS [64][256]: 2 rows/call
            int rb = wv * 8 + i * 2;
            int rl = rb + (lane >> 5);
            int ch = (lane & 31) ^ (rl & 7);
            gll16(Qb + (size_t)(j0 + rl) * D_DIM + ch * 8, qb + rb * 256);
        }
        #pragma unroll
        for (int i = 0; i < 4; ++i) {             // QtS [256][64]: 8 rows/call
            int rbase = wv * 32 + i * 8;
            int row = rbase + (lane >> 3);
            int ch = (lane & 7) ^ (lane >> 3);
            gll16(QT + (size_t)row * J_DIM + j0 + ch * 8, qt + rbase * 64);
        }
    };

    f32x4 oacc[4] = {};
    float psum[4] = {0.f, 0.f, 0.f, 0.f};
    float pmax[4] = {0.f, 0.f, 0.f, 0.f};

    stage_tiles(0, 0);
    asm volatile("s_waitcnt vmcnt(0)" ::: "memory");
    __builtin_amdgcn_sched_barrier(0);
    __builtin_amdgcn_s_barrier();
    __builtin_amdgcn_sched_barrier(0);

    for (int jt = 0; jt < 16; ++jt) {
        int cur = jt & 1;
        if (jt < 15) stage_tiles(cur ^ 1, (jt + 1) * 64);   // in-flight across barrier 1
        float qwv = qw[jt * 64 + nw * 16 + cidx];
        const unsigned short* qbc = qb0 + cur * 16384;
        const unsigned short* qtc = qt0 + cur * 16384;

        // S-phase: one 16x16 j-frag per wave, K=256 from registers x QbS
        f32x4 sacc = {0.f, 0.f, 0.f, 0.f};
        int brow = nw * 16 + cidx;
        #pragma unroll
        for (int f = 0; f < 8; ++f) {
            bf16x8 bq = __builtin_bit_cast(bf16x8,
                *(const u16x8*)(qbc + brow * 256 + (((f * 4 + rgrp) ^ (brow & 7)) << 3)));
            sacc = __builtin_amdgcn_mfma_f32_16x16x32_bf16(af[f], bq, sacc, 0, 0, 0);
        }
        // exp + reg row-stats + PS (swizzled)
        int prow0 = wm * 16 + rgrp * 4;
        int pcol = nw * 16 + cidx;
        #pragma unroll
        for (int reg = 0; reg < 4; ++reg) {
            float p = __expf(sacc[reg] + qwv);
            psum[reg] += p;
            pmax[reg] = fmaxf(pmax[reg], p);
            int pr = prow0 + reg;
            PS[pr * 64 + ((((pcol >> 3) ^ (pr & 7))) << 3) + (pcol & 7)] = f2bf(p);
        }
        wait_lgkm0_bar();   // PS visible; staging loads still in flight

        // PV: O(16t x 64d per wave) += P(16x64) @ Q(64 x 64d)
        #pragma unroll
        for (int ks = 0; ks < 2; ++ks) {
            int par = wm * 16 + cidx;
            bf16x8 pa = __builtin_bit_cast(bf16x8,
                *(const u16x8*)(PS + par * 64 + (((ks * 4 + rgrp) ^ (par & 7)) << 3)));
            #pragma unroll
            for (int nf = 0; nf < 4; ++nf) {
                int qr = nw * 64 + nf * 16 + cidx;
                bf16x8 qv = __builtin_bit_cast(bf16x8,
                    *(const u16x8*)(qtc + qr * 64 + (((ks * 4 + rgrp) ^ (qr & 7)) << 3)));
                oacc[nf] = __builtin_amdgcn_mfma_f32_16x16x32_bf16(pa, qv, oacc[nf], 0, 0, 0);
            }
        }
        wait_all_bar();     // next tiles staged + PS/buf reads done before overwrite
    }

    // ---- exact row stats
    #pragma unroll
    for (int reg = 0; reg < 4; ++reg) {
        #pragma unroll
        for (int o = 1; o < 16; o <<= 1) {
            psum[reg] += __shfl_xor(psum[reg], o);
            pmax[reg] = fmaxf(pmax[reg], __shfl_xor(pmax[reg], o));
        }
    }
    if (cidx == 0) {
        #pragma unroll
        for (int reg = 0; reg < 4; ++reg) {
            int row = wm * 16 + rgrp * 4 + reg;
            statS[nw * 32 + row] = psum[reg];
            statM[nw * 32 + row] = pmax[reg];
        }
    }
    __syncthreads();
    if (tid < 32) {
        float s = (statS[tid] + statS[32 + tid]) + (statS[64 + tid] + statS[96 + tid]);
        float mx = fmaxf(fmaxf(statM[tid], statM[32 + tid]),
                         fmaxf(statM[64 + tid], statM[96 + tid]));
        linvS[tid] = 1.0f / s;
        bS[tid] = __logf(mx) + cwS[tid];
    }
    __syncthreads();

    // ---- stage ctx f32 tile into freed qb0 area
    #pragma unroll
    for (int i = 0; i < 4; ++i) {
        int row = wv * 4 + i;
        gll16(ctx + (size_t)(t0 + row) * D_DIM + lane * 4, ctxS + row * 256);
    }
    asm volatile("s_waitcnt vmcnt(0)" ::: "memory");
    __builtin_amdgcn_sched_barrier(0);
    __syncthreads();

    // G col 0 (coalesced)
    #pragma unroll
    for (int i = 0; i < 4; ++i) {
        int idx = tid + i * 512;
        int row = idx >> 6, c4 = idx & 63;
        float4 v = *(const float4*)(ctxS + row * 256 + c4 * 4);
        *(float4*)(G + (size_t)(t0 + row) * 1024 + c4 * 4) = v;
    }
    // G cols 1,2 from O accumulators
    #pragma unroll
    for (int nf = 0; nf < 4; ++nf) {
        int col = nw * 64 + nf * 16 + cidx;
        #pragma unroll
        for (int reg = 0; reg < 4; ++reg) {
            int row = wm * 16 + rgrp * 4 + reg;
            float val = oacc[nf][reg] * linvS[row];
            float c = ctxS[row * 256 + col];
            float* gr = G + (size_t)(t0 + row) * 1024;
            gr[256 + col] = val;
            gr[512 + col] = c * val;
        }
    }
    // ht partial: 2 halves x 256 d
    int d = tid & 255, half = tid >> 8;
    float a = 0.f;
    #pragma unroll
    for (int r = 0; r < 16; ++r)
        a += bS[half * 16 + r] * ctxS[(half * 16 + r) * 256 + d];
    atomicAdd(ht + d, a);
}

// K2: G col 3 = ctx * htilde
__global__ __launch_bounds__(256) void g3_write(const float* __restrict__ ctx,
                                                const float* __restrict__ ht,
                                                float* __restrict__ G) {
    int gt = blockIdx.x * 256 + threadIdx.x;
    int idx = gt * 4;
    int t = idx >> 8, d = idx & 255;
    float4 c = *(const float4*)(ctx + (size_t)t * D_DIM + d);
    float4 h = *(const float4*)(ht + d);
    float4 o;
    o.x = c.x * h.x; o.y = c.y * h.y; o.z = c.z * h.z; o.w = c.w * h.w;
    *(float4*)(G + (size_t)t * 1024 + 768 + d) = o;
}

extern "C" void kernel_launch(void* const* d_in, const int* in_sizes, int n_in,
                              void* d_out, int out_size, void* d_ws, size_t ws_size,
                              hipStream_t stream) {
    (void)in_sizes; (void)n_in; (void)out_size; (void)ws_size;
    const float* ctx = (const float*)d_in[0];
    const float* qry = (const float*)d_in[1];
    const float* w   = (const float*)d_in[2];
    float* G = (float*)d_out;
    char* ws = (char*)d_ws;

    constexpr size_t OFF_QB = 0;                                    // 512 KiB
    constexpr size_t OFF_QT = OFF_QB + (size_t)J_DIM * D_DIM * 2;   // 512 KiB
    constexpr size_t OFF_QW = OFF_QT + (size_t)D_DIM * J_DIM * 2;   // 4 KiB
    constexpr size_t OFF_HT = OFF_QW + (size_t)J_DIM * 4;           // 1 KiB

    unsigned short* Qb = (unsigned short*)(ws + OFF_QB);
    unsigned short* QT = (unsigned short*)(ws + OFF_QT);
    float* qw = (float*)(ws + OFF_QW);
    float* ht = (float*)(ws + OFF_HT);

    constexpr int SMEM_BYTES = 136576;
    hipFuncSetAttribute((const void*)fused_main,
                        hipFuncAttributeMaxDynamicSharedMemorySize, SMEM_BYTES);

    prep_q<<<dim3(257), 256, 0, stream>>>(qry, w, Qb, QT, qw, ht);
    fused_main<<<dim3(T_DIM / 32), 512, SMEM_BYTES, stream>>>(ctx, w, Qb, QT, qw, ht, G);
    g3_write<<<dim3(T_DIM * D_DIM / 1024), 256, 0, stream>>>(ctx, ht, G);
}

// Round 9
// 47.282 us; speedup vs baseline: 1.2544x; 1.2544x over previous
//
#include <hip/hip_runtime.h>
#include <stdint.h>

#define T_DIM 8192
#define J_DIM 1024
#define D_DIM 256

typedef __bf16 bf16x8 __attribute__((ext_vector_type(8)));
typedef float f32x4 __attribute__((ext_vector_type(4)));
typedef unsigned short u16x8 __attribute__((ext_vector_type(8)));
typedef unsigned short u16x4 __attribute__((ext_vector_type(4)));

__device__ inline unsigned short f2bf(float x) {
    unsigned u = __builtin_bit_cast(unsigned, x);
    u += 0x7FFFu + ((u >> 16) & 1u);
    return (unsigned short)(u >> 16);
}

// async global->LDS, 16B/lane; LDS dest = wave-uniform base + lane*16 (linear);
// swizzle applied on the per-lane GLOBAL source address (both-sides rule #21).
__device__ inline void gll16(const void* g, void* l) {
    __builtin_amdgcn_global_load_lds(
        (const __attribute__((address_space(1))) unsigned int*)g,
        (__attribute__((address_space(3))) unsigned int*)l, 16, 0, 0);
}

// K0: fused prep. Blocks [0,2048): ctx -> Cm bf16 + cw. [2048,2304): qry -> Qb,QT,qw.
// [2304,2369): zero stats (lsum|rmax|ht).
__global__ __launch_bounds__(256) void prep_all(const float* __restrict__ ctx,
                                                const float* __restrict__ qry,
                                                const float* __restrict__ w,
                                                unsigned short* __restrict__ Cm,
                                                float* __restrict__ cw,
                                                unsigned short* __restrict__ Qb,
                                                unsigned short* __restrict__ QT,
                                                float* __restrict__ qw,
                                                float* __restrict__ stats) {
    int wid = threadIdx.x >> 6, lane = threadIdx.x & 63;
    if (blockIdx.x >= 2304) {
        int idx = (blockIdx.x - 2304) * 256 + threadIdx.x;
        if (idx < 2 * T_DIM + D_DIM) stats[idx] = 0.0f;
        return;
    }
    if (blockIdx.x < 2048) {
        int t = blockIdx.x * 4 + wid;
        float4 c  = *(const float4*)(ctx + (size_t)t * D_DIM + lane * 4);
        float4 wm = *(const float4*)(w + 2 * D_DIM + lane * 4);
        float4 wc = *(const float4*)(w + lane * 4);
        u16x4 cmv;
        cmv[0] = f2bf(c.x * wm.x);
        cmv[1] = f2bf(c.y * wm.y);
        cmv[2] = f2bf(c.z * wm.z);
        cmv[3] = f2bf(c.w * wm.w);
        *(u16x4*)(Cm + (size_t)t * D_DIM + lane * 4) = cmv;
        float s = c.x * wc.x + c.y * wc.y + c.z * wc.z + c.w * wc.w;
        #pragma unroll
        for (int o = 1; o < 64; o <<= 1) s += __shfl_xor(s, o);
        if (lane == 0) cw[t] = s;
    } else {
        int j = (blockIdx.x - 2048) * 4 + wid;
        float4 c  = *(const float4*)(qry + (size_t)j * D_DIM + lane * 4);
        float4 wq = *(const float4*)(w + D_DIM + lane * 4);
        u16x4 qv;
        qv[0] = f2bf(c.x);
        qv[1] = f2bf(c.y);
        qv[2] = f2bf(c.z);
        qv[3] = f2bf(c.w);
        *(u16x4*)(Qb + (size_t)j * D_DIM + lane * 4) = qv;
        int d0 = lane * 4;
        QT[(size_t)(d0 + 0) * J_DIM + j] = qv[0];
        QT[(size_t)(d0 + 1) * J_DIM + j] = qv[1];
        QT[(size_t)(d0 + 2) * J_DIM + j] = qv[2];
        QT[(size_t)(d0 + 3) * J_DIM + j] = qv[3];
        float s = c.x * wq.x + c.y * wq.y + c.z * wq.z + c.w * wq.w;
        #pragma unroll
        for (int o = 1; o < 64; o <<= 1) s += __shfl_xor(s, o);
        if (lane == 0) qw[j] = s;
    }
}

// K1: P = bf16(exp(Cm @ Qb^T + qw)) + fused row stats (atomics).
// 64x128 tile, BK=64, 4 waves (2m x 2n), grid 1024 -> ~4 blocks/CU.
__global__ __launch_bounds__(256) void gemm_s(const unsigned short* __restrict__ Cm,
                                              const unsigned short* __restrict__ Qb,
                                              const float* __restrict__ qw,
                                              unsigned short* __restrict__ P,
                                              float* __restrict__ lsum,
                                              int* __restrict__ rmax) {
    __shared__ unsigned short SH[12288];   // As [64][64] (4096) | Bs [128][64] (8192)
    __shared__ float statS[2][64];
    __shared__ float statM[2][64];
    unsigned short* As = SH;
    unsigned short* Bs = SH + 4096;
    int tid = threadIdx.x, lane = tid & 63, wv = tid >> 6;
    int wm = wv >> 1, wn = wv & 1;
    int bm = blockIdx.x & 127, bn = blockIdx.x >> 7;
    int cidx = lane & 15, rgrp = lane >> 4;
    int srow8 = lane >> 3;                 // row within 8-row group
    int swzc = (lane & 7) ^ srow8;         // inverse-swizzled source chunk
    f32x4 acc[2][4] = {};

    const unsigned short* Asrc = Cm + (size_t)(bm * 64 + srow8) * 256 + (swzc << 3);
    const unsigned short* Bsrc = Qb + (size_t)(bn * 128 + srow8) * 256 + (swzc << 3);

    for (int k0 = 0; k0 < 256; k0 += 64) {
        if (k0) __syncthreads();
        #pragma unroll
        for (int i = 0; i < 2; ++i) {      // A: 8 groups, 2 per wave
            int g = wv * 2 + i;
            gll16(Asrc + (size_t)(g * 8) * 256 + k0, As + g * 512);
        }
        #pragma unroll
        for (int i = 0; i < 4; ++i) {      // B: 16 groups, 4 per wave
            int g = wv * 4 + i;
            gll16(Bsrc + (size_t)(g * 8) * 256 + k0, Bs + g * 512);
        }
        __syncthreads();
        #pragma unroll
        for (int ks = 0; ks < 2; ++ks) {
            int klo = ks * 4 + rgrp;
            bf16x8 af[2], bfr[4];
            #pragma unroll
            for (int m = 0; m < 2; ++m) {
                int ra = wm * 32 + m * 16 + cidx;
                af[m] = __builtin_bit_cast(bf16x8,
                        *(const u16x8*)(As + ra * 64 + ((klo ^ (ra & 7)) << 3)));
            }
            #pragma unroll
            for (int n = 0; n < 4; ++n) {
                int rb = wn * 64 + n * 16 + cidx;
                bfr[n] = __builtin_bit_cast(bf16x8,
                        *(const u16x8*)(Bs + rb * 64 + ((klo ^ (rb & 7)) << 3)));
            }
            #pragma unroll
            for (int m = 0; m < 2; ++m)
                #pragma unroll
                for (int n = 0; n < 4; ++n)
                    acc[m][n] = __builtin_amdgcn_mfma_f32_16x16x32_bf16(af[m], bfr[n], acc[m][n], 0, 0, 0);
        }
    }

    // exp + per-row stats
    float qwv[4];
    #pragma unroll
    for (int n = 0; n < 4; ++n) qwv[n] = qw[bn * 128 + wn * 64 + n * 16 + cidx];
    #pragma unroll
    for (int m = 0; m < 2; ++m) {
        #pragma unroll
        for (int rg = 0; rg < 4; ++rg) {
            float s = 0.f, mx = 0.f;
            #pragma unroll
            for (int n = 0; n < 4; ++n) {
                float p = __expf(acc[m][n][rg] + qwv[n]);
                acc[m][n][rg] = p;
                s += p;
                mx = fmaxf(mx, p);
            }
            #pragma unroll
            for (int o = 1; o < 16; o <<= 1) {
                s += __shfl_xor(s, o);
                mx = fmaxf(mx, __shfl_xor(mx, o));
            }
            if (cidx == 0) {
                int row = wm * 32 + m * 16 + rgrp * 4 + rg;
                statS[wn][row] = s;
                statM[wn][row] = mx;
            }
        }
    }
    __syncthreads();
    if (tid < 64) {
        atomicAdd(lsum + bm * 64 + tid, statS[0][tid] + statS[1][tid]);
        atomicMax(rmax + bm * 64 + tid,
                  __float_as_int(fmaxf(statM[0][tid], statM[1][tid])));
    }

    // restage P tile [64][128] (swizzled) + coalesced u16x8 stores
    #pragma unroll
    for (int m = 0; m < 2; ++m)
        #pragma unroll
        for (int n = 0; n < 4; ++n)
            #pragma unroll
            for (int rg = 0; rg < 4; ++rg) {
                int row = wm * 32 + m * 16 + rgrp * 4 + rg;
                int col = wn * 64 + n * 16 + cidx;
                SH[row * 128 + (((col >> 3) ^ (row & 7)) << 3) + (col & 7)] = f2bf(acc[m][n][rg]);
            }
    __syncthreads();
    #pragma unroll
    for (int i = 0; i < 4; ++i) {
        int r = i * 16 + (tid >> 4);
        int c8 = tid & 15;
        u16x8 v = *(const u16x8*)(SH + r * 128 + ((c8 ^ (r & 7)) << 3));
        *(u16x8*)(P + (size_t)(bm * 64 + r) * J_DIM + bn * 128 + c8 * 8) = v;
    }
}

// K2: b = log(rmax)+cw, ht[d] += sum_t b*ctx. 128 blocks x 64 rows.
__global__ __launch_bounds__(256) void hb_kernel(const float* __restrict__ rmaxf,
                                                 const float* __restrict__ cw,
                                                 const float* __restrict__ ctx,
                                                 float* __restrict__ ht) {
    __shared__ float bsh[64];
    int tid = threadIdx.x;
    int t0b = blockIdx.x * 64;
    if (tid < 64) bsh[tid] = __logf(rmaxf[t0b + tid]) + cw[t0b + tid];
    __syncthreads();
    float pb = 0.f;
    #pragma unroll 8
    for (int r = 0; r < 64; ++r)
        pb += bsh[r] * ctx[(size_t)(t0b + r) * D_DIM + tid];
    atomicAdd(ht + tid, pb);
}

// K3: O = P @ query (QT rows = B^T); epilogue writes all 4 G col-blocks.
// 64x64 tile, BK=64, 4 waves (2m x 2n), grid 512 -> multiple blocks/CU.
__global__ __launch_bounds__(256) void gemm_o(const unsigned short* __restrict__ P,
                                              const unsigned short* __restrict__ QT,
                                              const float* __restrict__ lsum,
                                              const float* __restrict__ ht,
                                              const float* __restrict__ ctx,
                                              float* __restrict__ G) {
    __shared__ unsigned short As[4096];    // [64][64]
    __shared__ unsigned short Bs[4096];    // [64][64]
    int tid = threadIdx.x, lane = tid & 63, wv = tid >> 6;
    int wm = wv >> 1, wn = wv & 1;
    int bm = blockIdx.x & 127, bn = blockIdx.x >> 7;
    int cidx = lane & 15, rgrp = lane >> 4;
    int srow8 = lane >> 3;
    int swzc = (lane & 7) ^ srow8;
    f32x4 acc[2][2] = {};

    const unsigned short* Ap = P  + (size_t)(bm * 64 + srow8) * J_DIM + (swzc << 3);
    const unsigned short* Bp = QT + (size_t)(bn * 64 + srow8) * J_DIM + (swzc << 3);

    for (int k0 = 0; k0 < 1024; k0 += 64) {
        if (k0) __syncthreads();
        #pragma unroll
        for (int i = 0; i < 2; ++i) {      // A: 8 groups, 2 per wave
            int g = wv * 2 + i;
            gll16(Ap + (size_t)(g * 8) * J_DIM + k0, As + g * 512);
        }
        #pragma unroll
        for (int i = 0; i < 2; ++i) {      // B: 8 groups, 2 per wave
            int g = wv * 2 + i;
            gll16(Bp + (size_t)(g * 8) * J_DIM + k0, Bs + g * 512);
        }
        __syncthreads();
        #pragma unroll
        for (int ks = 0; ks < 2; ++ks) {
            int klo = ks * 4 + rgrp;
            bf16x8 af[2], bfr[2];
            #pragma unroll
            for (int m = 0; m < 2; ++m) {
                int ra = wm * 32 + m * 16 + cidx;
                af[m] = __builtin_bit_cast(bf16x8,
                        *(const u16x8*)(As + ra * 64 + ((klo ^ (ra & 7)) << 3)));
            }
            #pragma unroll
            for (int n = 0; n < 2; ++n) {
                int rb = wn * 32 + n * 16 + cidx;
                bfr[n] = __builtin_bit_cast(bf16x8,
                        *(const u16x8*)(Bs + rb * 64 + ((klo ^ (rb & 7)) << 3)));
            }
            #pragma unroll
            for (int m = 0; m < 2; ++m)
                #pragma unroll
                for (int n = 0; n < 2; ++n)
                    acc[m][n] = __builtin_amdgcn_mfma_f32_16x16x32_bf16(af[m], bfr[n], acc[m][n], 0, 0, 0);
        }
    }

    float htv[2];
    #pragma unroll
    for (int n = 0; n < 2; ++n) htv[n] = ht[bn * 64 + wn * 32 + n * 16 + cidx];
    #pragma unroll
    for (int m = 0; m < 2; ++m) {
        #pragma unroll
        for (int rg = 0; rg < 4; ++rg) {
            int t = bm * 64 + wm * 32 + m * 16 + rgrp * 4 + rg;
            float linv = 1.0f / lsum[t];
            float* gr = G + (size_t)t * 1024;
            #pragma unroll
            for (int n = 0; n < 2; ++n) {
                int d = bn * 64 + wn * 32 + n * 16 + cidx;
                float val = acc[m][n][rg] * linv;
                float c = ctx[(size_t)t * D_DIM + d];
                gr[d]       = c;
                gr[256 + d] = val;
                gr[512 + d] = c * val;
                gr[768 + d] = c * htv[n];
            }
        }
    }
}

extern "C" void kernel_launch(void* const* d_in, const int* in_sizes, int n_in,
                              void* d_out, int out_size, void* d_ws, size_t ws_size,
                              hipStream_t stream) {
    (void)in_sizes; (void)n_in; (void)out_size; (void)ws_size;
    const float* ctx = (const float*)d_in[0];
    const float* qry = (const float*)d_in[1];
    const float* w   = (const float*)d_in[2];
    float* G = (float*)d_out;
    char* ws = (char*)d_ws;

    constexpr size_t OFF_P  = 0;                                   // 16 MiB
    constexpr size_t OFF_CM = OFF_P  + (size_t)T_DIM * J_DIM * 2;  // 4 MiB
    constexpr size_t OFF_QB = OFF_CM + (size_t)T_DIM * D_DIM * 2;
    constexpr size_t OFF_QT = OFF_QB + (size_t)J_DIM * D_DIM * 2;
    constexpr size_t OFF_CW = OFF_QT + (size_t)D_DIM * J_DIM * 2;
    constexpr size_t OFF_QW = OFF_CW + (size_t)T_DIM * 4;
    constexpr size_t OFF_ST = OFF_QW + (size_t)J_DIM * 4;

    unsigned short* P  = (unsigned short*)(ws + OFF_P);
    unsigned short* Cm = (unsigned short*)(ws + OFF_CM);
    unsigned short* Qb = (unsigned short*)(ws + OFF_QB);
    unsigned short* QT = (unsigned short*)(ws + OFF_QT);
    float* cw    = (float*)(ws + OFF_CW);
    float* qw    = (float*)(ws + OFF_QW);
    float* stats = (float*)(ws + OFF_ST);
    float* lsum  = stats;                 // 8192
    float* rmax  = stats + T_DIM;         // 8192 (float bits via int atomicMax)
    float* ht    = stats + 2 * T_DIM;     // 256

    prep_all<<<dim3(2369), 256, 0, stream>>>(ctx, qry, w, Cm, cw, Qb, QT, qw, stats);
    gemm_s<<<dim3(1024), 256, 0, stream>>>(Cm, Qb, qw, P, lsum, (int*)rmax);
    hb_kernel<<<dim3(128), 256, 0, stream>>>(rmax, cw, ctx, ht);
    gemm_o<<<dim3(512), 256, 0, stream>>>(P, QT, lsum, ht, ctx, G);
}